// Round 17
// baseline (145.205 us; speedup 1.0000x reference)
//
#include <hip/hip_runtime.h>
#include <hip/hip_bf16.h>
#include <math.h>

#define B_ 4
#define N_ 256
#define D_ 128
#define H_ 256
#define K_ 8

typedef __attribute__((ext_vector_type(8))) short short8;
typedef __attribute__((ext_vector_type(4))) float f32x4;

__device__ __forceinline__ unsigned short f2bf(float x) {
    union { __hip_bfloat16 h; unsigned short s; } u;
    u.h = __float2bfloat16(x);
    return u.s;
}
__device__ __forceinline__ float bf2f(unsigned short b) {
    unsigned v = ((unsigned)b) << 16;
    return __builtin_bit_cast(float, v);
}
__device__ __forceinline__ unsigned pk2(float x, float y) {
    union { __hip_bfloat162 h; unsigned u; } c;
    c.h = __float22bfloat162_rn(float2{x, y});
    return c.u;
}

// K0 v2 (unchanged from R16).
__global__ __launch_bounds__(256) void pre_kernel(
    const float* __restrict__ s, const float* __restrict__ W1,
    const float* __restrict__ b1,
    float* __restrict__ avec, float* __restrict__ bvec,
    unsigned short* __restrict__ Wt)
{
    int blk = blockIdx.x;
    int t = threadIdx.x;
    if (blk < 512) {
        int bi0 = blk * 2;
        __shared__ float s2[2][D_];
        {
            int r = t >> 7, d = t & 127;
            s2[r][d] = s[(size_t)(bi0 + r) * D_ + d];
        }
        __syncthreads();
        float aA0 = b1[t], aA1 = aA0, aB0 = 0.f, aB1 = 0.f;
        const float* W1a = W1 + t;
        const float* W1b = W1 + (size_t)D_ * H_ + t;
        #pragma unroll 8
        for (int d = 0; d < D_; ++d) {
            float wa = W1a[(size_t)d * H_];
            float wb = W1b[(size_t)d * H_];
            float s0 = s2[0][d], s1 = s2[1][d];
            aA0 = fmaf(s0, wa, aA0);
            aA1 = fmaf(s1, wa, aA1);
            aB0 = fmaf(s0, wb, aB0);
            aB1 = fmaf(s1, wb, aB1);
        }
        avec[(size_t)bi0 * H_ + t]       = aA0;
        avec[(size_t)(bi0 + 1) * H_ + t] = aA1;
        bvec[(size_t)bi0 * H_ + t]       = aB0;
        bvec[(size_t)(bi0 + 1) * H_ + t] = aB1;
    } else {
        int e = (blk - 512) * 256 + t;
        int h = e >> 7, d = e & 127;
        Wt[e] = f2bf(W1[(size_t)(2 * D_ + d) * H_ + h]);
    }
}

// K1 v5: ONLY change vs v4: ic = 8 i-rows per block -> 512 blocks = 2
// co-resident blocks/CU (LDS 40 KB). v4's 256-block grid was 1 block/CU:
// every per-iteration barrier exposed the staging-load latency to ALL
// resident waves. Second block fills those stalls.
__global__ __launch_bounds__(512, 2) void approx_scores(
    const float* __restrict__ s, const unsigned short* __restrict__ Wt,
    const float* __restrict__ W2, const float* __restrict__ b2,
    const float* __restrict__ avec, const float* __restrict__ bvec,
    unsigned short* __restrict__ ascu)
{
    int blk = blockIdx.x;              // 512 = b(4) x jt(4) x ic(32)
    int b   = blk >> 7;
    int jtb = ((blk >> 5) & 3) * 64;
    int i0  = (blk & 31) * 8;
    int t = threadIdx.x;
    int lane = t & 63;
    int w = __builtin_amdgcn_readfirstlane(t >> 6);    // wave 0..7 -> 32-h slice
    int l15 = lane & 15, quad = lane >> 4;

    __shared__ __align__(16) short Pl[2][64 * 128];    // 32 KB (dbuf)
    __shared__ __align__(16) float si_all[8][D_];      // 4 KB
    __shared__ float partial[2][8][64];                // 4 KB

    const float* sB = s + (size_t)b * N_ * D_;

    if (t < 256) {
        int ii = t >> 5, dq = t & 31;
        *(float4*)&si_all[ii][dq * 4] =
            *(const float4*)(sB + (size_t)(i0 + ii) * D_ + dq * 4);
    }

    short8 Wreg[2][4];
    #pragma unroll
    for (int mi = 0; mi < 2; ++mi)
        #pragma unroll
        for (int dk = 0; dk < 4; ++dk)
            Wreg[mi][dk] = *(const short8*)(
                Wt + (size_t)(w * 32 + mi * 16 + l15) * D_ + dk * 32 + quad * 8);
    float bvr[2][4][4];
    float w2r[2][4];
    #pragma unroll
    for (int mi = 0; mi < 2; ++mi) {
        int hq = w * 32 + mi * 16 + quad * 4;
        #pragma unroll
        for (int r = 0; r < 4; ++r)
            w2r[mi][r] = W2[hq + r];
        #pragma unroll
        for (int nj = 0; nj < 4; ++nj)
            #pragma unroll
            for (int r = 0; r < 4; ++r)
                bvr[mi][nj][r] = bvec[((size_t)(b * N_ + jtb + nj * 16 + l15)) * H_
                                      + hq + r];
    }
    float b2v = b2[0];
    __syncthreads();

    {
        int row = t >> 3, seg = t & 7;
        const float* sj = sB + (size_t)(jtb + row) * D_ + seg * 16;
        float4 a0 = ((const float4*)sj)[0], a1 = ((const float4*)sj)[1];
        float4 a2 = ((const float4*)sj)[2], a3 = ((const float4*)sj)[3];
        const float* si = &si_all[0][seg * 16];
        float4 s0 = ((const float4*)si)[0], s1 = ((const float4*)si)[1];
        float4 s2 = ((const float4*)si)[2], s3 = ((const float4*)si)[3];
        uint4 v0, v1;
        v0.x = pk2(a0.x * s0.x, a0.y * s0.y); v0.y = pk2(a0.z * s0.z, a0.w * s0.w);
        v0.z = pk2(a1.x * s1.x, a1.y * s1.y); v0.w = pk2(a1.z * s1.z, a1.w * s1.w);
        v1.x = pk2(a2.x * s2.x, a2.y * s2.y); v1.y = pk2(a2.z * s2.z, a2.w * s2.w);
        v1.z = pk2(a3.x * s3.x, a3.y * s3.y); v1.w = pk2(a3.z * s3.z, a3.w * s3.w);
        int pc0 = (seg * 2) ^ (row & 15), pc1 = (seg * 2 + 1) ^ (row & 15);
        *(uint4*)&Pl[0][row * 128 + pc0 * 8] = v0;
        *(uint4*)&Pl[0][row * 128 + pc1 * 8] = v1;
    }
    __syncthreads();

    #pragma unroll 1
    for (int i = 0; i < 8; ++i) {
        int cur = i & 1;
        if (w == 0 && i > 0) {
            float sum = b2v;
            #pragma unroll
            for (int ww = 0; ww < 8; ++ww) sum += partial[(i - 1) & 1][ww][lane];
            ascu[(size_t)(b * N_ + i0 + i - 1) * N_ + jtb + lane] = f2bf(sum);
        }
        float avc[2][4];
        #pragma unroll
        for (int mi = 0; mi < 2; ++mi) {
            int hq = w * 32 + mi * 16 + quad * 4;
            #pragma unroll
            for (int r = 0; r < 4; ++r)
                avc[mi][r] = avec[(size_t)(b * N_ + i0 + i) * H_ + hq + r];
        }
        f32x4 acc[2][4];
        #pragma unroll
        for (int mi = 0; mi < 2; ++mi)
            #pragma unroll
            for (int nj = 0; nj < 4; ++nj)
                acc[mi][nj] = (f32x4){0.f, 0.f, 0.f, 0.f};
        #pragma unroll
        for (int dk = 0; dk < 4; ++dk) {
            short8 Pf[4];
            #pragma unroll
            for (int nj = 0; nj < 4; ++nj) {
                int pcc = (dk * 4 + quad) ^ l15;
                Pf[nj] = *(const short8*)&Pl[cur][(nj * 16 + l15) * 128 + pcc * 8];
            }
            #pragma unroll
            for (int nj = 0; nj < 4; ++nj)
                #pragma unroll
                for (int mi = 0; mi < 2; ++mi)
                    acc[mi][nj] = __builtin_amdgcn_mfma_f32_16x16x32_bf16(
                        Wreg[mi][dk], Pf[nj], acc[mi][nj], 0, 0, 0);
        }
        if (i < 7) {
            int row = t >> 3, seg = t & 7;
            const float* sj = sB + (size_t)(jtb + row) * D_ + seg * 16;
            float4 a0 = ((const float4*)sj)[0], a1 = ((const float4*)sj)[1];
            float4 a2 = ((const float4*)sj)[2], a3 = ((const float4*)sj)[3];
            const float* si = &si_all[i + 1][seg * 16];
            float4 s0 = ((const float4*)si)[0], s1 = ((const float4*)si)[1];
            float4 s2 = ((const float4*)si)[2], s3 = ((const float4*)si)[3];
            uint4 v0, v1;
            v0.x = pk2(a0.x * s0.x, a0.y * s0.y); v0.y = pk2(a0.z * s0.z, a0.w * s0.w);
            v0.z = pk2(a1.x * s1.x, a1.y * s1.y); v0.w = pk2(a1.z * s1.z, a1.w * s1.w);
            v1.x = pk2(a2.x * s2.x, a2.y * s2.y); v1.y = pk2(a2.z * s2.z, a2.w * s2.w);
            v1.z = pk2(a3.x * s3.x, a3.y * s3.y); v1.w = pk2(a3.z * s3.z, a3.w * s3.w);
            int pc0 = (seg * 2) ^ (row & 15), pc1 = (seg * 2 + 1) ^ (row & 15);
            *(uint4*)&Pl[cur ^ 1][row * 128 + pc0 * 8] = v0;
            *(uint4*)&Pl[cur ^ 1][row * 128 + pc1 * 8] = v1;
        }
        float rs[4];
        #pragma unroll
        for (int nj = 0; nj < 4; ++nj) rs[nj] = 0.f;
        #pragma unroll
        for (int mi = 0; mi < 2; ++mi)
            #pragma unroll
            for (int nj = 0; nj < 4; ++nj)
                #pragma unroll
                for (int r = 0; r < 4; ++r) {
                    float z = acc[mi][nj][r] + avc[mi][r] + bvr[mi][nj][r];
                    rs[nj] = fmaf(fmaxf(z, 0.f), w2r[mi][r], rs[nj]);
                }
        #pragma unroll
        for (int nj = 0; nj < 4; ++nj) {
            rs[nj] += __shfl_xor(rs[nj], 16);
            rs[nj] += __shfl_xor(rs[nj], 32);
        }
        float v = (quad == 0) ? rs[0] : (quad == 1) ? rs[1] : (quad == 2) ? rs[2] : rs[3];
        partial[cur][w][lane] = v;
        __syncthreads();
    }
    if (w == 0) {
        float sum = b2v;
        #pragma unroll
        for (int ww = 0; ww < 8; ++ww) sum += partial[7 & 1][ww][lane];
        ascu[(size_t)(b * N_ + i0 + 7) * N_ + jtb + lane] = f2bf(sum);
    }
}

// K2: R12's measured-fastest config (unchanged from R16).
#define DCH 32
__global__ __launch_bounds__(512, 4) void finalize_kernel(
    const float* __restrict__ s, const float* __restrict__ W1,
    const float* __restrict__ W2, const float* __restrict__ b2,
    const float* __restrict__ avec, const float* __restrict__ bvec,
    const unsigned short* __restrict__ ascu,
    float* __restrict__ ctx, float* __restrict__ gate, float* __restrict__ w)
{
    int bi0 = blockIdx.x * 2;          // 512 blocks
    int b = bi0 >> 8;
    int t = threadIdx.x;               // 0..511

    __shared__ float asc[2][N_];
    __shared__ int cand[2][16];
    __shared__ __align__(16) float Pt[D_][32];
    __shared__ __align__(16) float Wl[DCH][H_];
    __shared__ float part[32][33];
    __shared__ float rsc[2][16];
    __shared__ int sel8[2][8];

    {
        int tr = t >> 8, jj = t & 255;
        asc[tr][jj] = bf2f(ascu[(size_t)(bi0 + tr) * N_ + jj]);
    }
    __syncthreads();
    {
        int tr = t >> 8, jj = t & 255;
        float my = asc[tr][jj];
        int rank = 0;
        #pragma unroll 8
        for (int j2 = 0; j2 < N_; ++j2) {
            float o = asc[tr][j2];
            rank += (o > my) || (o == my && j2 < jj);
        }
        if (rank < 16) cand[tr][rank] = jj;
    }
    __syncthreads();

    const float* Wc = W1 + (size_t)2 * D_ * H_;

    float4 wpre[4];
    #pragma unroll
    for (int k = 0; k < 4; ++k) {
        int q = t + 512 * k;
        int dd = q >> 6, hh = (q & 63) * 4;
        wpre[k] = *(const float4*)(Wc + (size_t)dd * H_ + hh);
    }

    #pragma unroll
    for (int e = t; e < 1024; e += 512) {
        int p = e & 31, dq = e >> 5;
        int r = p >> 4, c = p & 15;
        int j = cand[r][c];
        float4 sj = *(const float4*)(s + ((size_t)(b * N_ + j)) * D_ + dq * 4);
        float4 si = *(const float4*)(s + ((size_t)(bi0 + r)) * D_ + dq * 4);
        Pt[dq * 4 + 0][p] = si.x * sj.x;
        Pt[dq * 4 + 1][p] = si.y * sj.y;
        Pt[dq * 4 + 2][p] = si.z * sj.z;
        Pt[dq * 4 + 3][p] = si.w * sj.w;
    }

    int pg = t & 15, hg = t >> 4;
    int h0 = hg * 8;
    float acc[2][8];
    #pragma unroll
    for (int pp = 0; pp < 2; ++pp) {
        int p = pg * 2 + pp;
        int r = p >> 4, c = p & 15;
        int j = cand[r][c];
        const float* av = avec + (size_t)(bi0 + r) * H_ + h0;
        const float* bv = bvec + ((size_t)(b * N_ + j)) * H_ + h0;
        #pragma unroll
        for (int m4 = 0; m4 < 2; ++m4) {
            float4 a4 = *(const float4*)(av + m4 * 4);
            float4 b4 = *(const float4*)(bv + m4 * 4);
            acc[pp][m4 * 4 + 0] = a4.x + b4.x;
            acc[pp][m4 * 4 + 1] = a4.y + b4.y;
            acc[pp][m4 * 4 + 2] = a4.z + b4.z;
            acc[pp][m4 * 4 + 3] = a4.w + b4.w;
        }
    }
    __syncthreads();

    for (int ch = 0; ch < 4; ++ch) {
        #pragma unroll
        for (int k = 0; k < 4; ++k) {
            int q = t + 512 * k;
            int dd = q >> 6, hh = (q & 63) * 4;
            *(float4*)&Wl[dd][hh] = wpre[k];
        }
        __syncthreads();
        if (ch < 3) {
            int d0n = (ch + 1) * DCH;
            #pragma unroll
            for (int k = 0; k < 4; ++k) {
                int q = t + 512 * k;
                int dd = q >> 6, hh = (q & 63) * 4;
                wpre[k] = *(const float4*)(Wc + (size_t)(d0n + dd) * H_ + hh);
            }
        }
        int d0 = ch * DCH;
        #pragma unroll
        for (int d = 0; d < DCH; ++d) {
            float2 pv = *(const float2*)&Pt[d0 + d][pg * 2];
            float wv[8];
            *(float4*)&wv[0] = *(const float4*)&Wl[d][h0];
            *(float4*)&wv[4] = *(const float4*)&Wl[d][h0 + 4];
            #pragma unroll
            for (int m = 0; m < 8; ++m) {
                acc[0][m] = fmaf(pv.x, wv[m], acc[0][m]);
                acc[1][m] = fmaf(pv.y, wv[m], acc[1][m]);
            }
        }
        __syncthreads();
    }

    {
        float w2v[8];
        *(float4*)&w2v[0] = *(const float4*)(W2 + h0);
        *(float4*)&w2v[4] = *(const float4*)(W2 + h0 + 4);
        #pragma unroll
        for (int pp = 0; pp < 2; ++pp) {
            float sc = 0.f;
            #pragma unroll
            for (int m = 0; m < 8; ++m)
                sc = fmaf(fmaxf(acc[pp][m], 0.f), w2v[m], sc);
            part[pg * 2 + pp][hg] = sc;
        }
    }
    __syncthreads();
    if (t < 32) {
        float sum = b2[0];
        #pragma unroll
        for (int m = 0; m < 32; ++m) sum += part[t][m];
        rsc[t >> 4][t & 15] = sum;
    }
    __syncthreads();

    if (t < 32) {
        int rr = t >> 4, cc = t & 15;
        float my = rsc[rr][cc]; int myj = cand[rr][cc];
        int rank = 0;
        #pragma unroll
        for (int c2 = 0; c2 < 16; ++c2) {
            float o = rsc[rr][c2]; int oj = cand[rr][c2];
            rank += (o > my) || (o == my && oj < myj);
        }
        if (rank < 8) sel8[rr][rank] = myj;
    }
    __syncthreads();

    {
        int rr = t >> 8, jj = t & 255;
        float gv = 0.f;
        #pragma unroll
        for (int m = 0; m < 8; ++m)
            gv = (jj == sel8[rr][m]) ? 1.f : gv;
        gate[(size_t)(bi0 + rr) * N_ + jj] = gv;
        w[(size_t)(bi0 + rr) * N_ + jj]    = gv * 0.125f;
    }
    if (t < 256) {
        int rr = t >> 7, d = t & 127;
        float a = 0.f;
        #pragma unroll
        for (int m = 0; m < 8; ++m)
            a += s[((size_t)(b * N_ + sel8[rr][m])) * D_ + d];
        ctx[(size_t)(bi0 + rr) * D_ + d] = a * 0.125f;
    }
}

extern "C" void kernel_launch(void* const* d_in, const int* in_sizes, int n_in,
                              void* d_out, int out_size, void* d_ws, size_t ws_size,
                              hipStream_t stream)
{
    const float* s  = (const float*)d_in[0];
    const float* W1 = (const float*)d_in[1];
    const float* b1 = (const float*)d_in[2];
    const float* W2 = (const float*)d_in[3];
    const float* b2 = (const float*)d_in[4];

    float* avec = (float*)d_ws;                                           // 262144 f
    float* bvec = avec + (size_t)B_ * N_ * H_;                            // 262144 f
    unsigned short* ascu = (unsigned short*)(bvec + (size_t)B_ * N_ * H_);// 262144 us
    unsigned short* Wtu  = ascu + (size_t)B_ * N_ * N_;                   // 32768 us

    float* ctx  = (float*)d_out;
    float* gate = ctx + (size_t)B_ * N_ * D_;
    float* wout = gate + (size_t)B_ * N_ * N_;

    pre_kernel<<<640, 256, 0, stream>>>(s, W1, b1, avec, bvec, Wtu);
    approx_scores<<<512, 512, 0, stream>>>(s, Wtu, W2, b2, avec, bvec, ascu);
    finalize_kernel<<<B_ * N_ / 2, 512, 0, stream>>>(s, W1, W2, b2, avec, bvec, ascu,
                                                     ctx, gate, wout);
}

// Round 18
// 141.697 us; speedup vs baseline: 1.0248x; 1.0248x over previous
//
#include <hip/hip_runtime.h>
#include <hip/hip_bf16.h>
#include <math.h>

#define B_ 4
#define N_ 256
#define D_ 128
#define H_ 256
#define K_ 8

typedef __attribute__((ext_vector_type(8))) short short8;
typedef __attribute__((ext_vector_type(4))) float f32x4;

__device__ __forceinline__ unsigned short f2bf(float x) {
    union { __hip_bfloat16 h; unsigned short s; } u;
    u.h = __float2bfloat16(x);
    return u.s;
}
__device__ __forceinline__ float bf2f(unsigned short b) {
    unsigned v = ((unsigned)b) << 16;
    return __builtin_bit_cast(float, v);
}
__device__ __forceinline__ unsigned pk2(float x, float y) {
    union { __hip_bfloat162 h; unsigned u; } c;
    c.h = __float22bfloat162_rn(float2{x, y});
    return c.u;
}
// async global->LDS, 16 B per lane (m97-verified width); no VGPR round-trip
__device__ __forceinline__ void gld_lds16(const float* g, float* l) {
    __builtin_amdgcn_global_load_lds(
        (const __attribute__((address_space(1))) void*)g,
        (__attribute__((address_space(3))) void*)l, 16, 0, 0);
}

// K0 v2 (unchanged from R16).
__global__ __launch_bounds__(256) void pre_kernel(
    const float* __restrict__ s, const float* __restrict__ W1,
    const float* __restrict__ b1,
    float* __restrict__ avec, float* __restrict__ bvec,
    unsigned short* __restrict__ Wt)
{
    int blk = blockIdx.x;
    int t = threadIdx.x;
    if (blk < 512) {
        int bi0 = blk * 2;
        __shared__ float s2[2][D_];
        {
            int r = t >> 7, d = t & 127;
            s2[r][d] = s[(size_t)(bi0 + r) * D_ + d];
        }
        __syncthreads();
        float aA0 = b1[t], aA1 = aA0, aB0 = 0.f, aB1 = 0.f;
        const float* W1a = W1 + t;
        const float* W1b = W1 + (size_t)D_ * H_ + t;
        #pragma unroll 8
        for (int d = 0; d < D_; ++d) {
            float wa = W1a[(size_t)d * H_];
            float wb = W1b[(size_t)d * H_];
            float s0 = s2[0][d], s1 = s2[1][d];
            aA0 = fmaf(s0, wa, aA0);
            aA1 = fmaf(s1, wa, aA1);
            aB0 = fmaf(s0, wb, aB0);
            aB1 = fmaf(s1, wb, aB1);
        }
        avec[(size_t)bi0 * H_ + t]       = aA0;
        avec[(size_t)(bi0 + 1) * H_ + t] = aA1;
        bvec[(size_t)bi0 * H_ + t]       = aB0;
        bvec[(size_t)(bi0 + 1) * H_ + t] = aB1;
    } else {
        int e = (blk - 512) * 256 + t;
        int h = e >> 7, d = e & 127;
        Wt[e] = f2bf(W1[(size_t)(2 * D_ + d) * H_ + h]);
    }
}

// K1 v4 (reverted to R16's best: ic=16, 256 blocks; v5's 512-block split regressed).
__global__ __launch_bounds__(512, 2) void approx_scores(
    const float* __restrict__ s, const unsigned short* __restrict__ Wt,
    const float* __restrict__ W2, const float* __restrict__ b2,
    const float* __restrict__ avec, const float* __restrict__ bvec,
    unsigned short* __restrict__ ascu)
{
    int blk = blockIdx.x;              // 256 = b(4) x jt(4) x ic(16)
    int b   = blk >> 6;
    int jtb = ((blk >> 4) & 3) * 64;
    int i0  = (blk & 15) * 16;
    int t = threadIdx.x;
    int lane = t & 63;
    int w = __builtin_amdgcn_readfirstlane(t >> 6);
    int l15 = lane & 15, quad = lane >> 4;

    __shared__ __align__(16) short Pl[2][64 * 128];
    __shared__ __align__(16) float si_all[16][D_];
    __shared__ float partial[2][8][64];

    const float* sB = s + (size_t)b * N_ * D_;

    {
        int ii = t >> 5, dq = t & 31;
        *(float4*)&si_all[ii][dq * 4] =
            *(const float4*)(sB + (size_t)(i0 + ii) * D_ + dq * 4);
    }

    short8 Wreg[2][4];
    #pragma unroll
    for (int mi = 0; mi < 2; ++mi)
        #pragma unroll
        for (int dk = 0; dk < 4; ++dk)
            Wreg[mi][dk] = *(const short8*)(
                Wt + (size_t)(w * 32 + mi * 16 + l15) * D_ + dk * 32 + quad * 8);
    float bvr[2][4][4];
    float w2r[2][4];
    #pragma unroll
    for (int mi = 0; mi < 2; ++mi) {
        int hq = w * 32 + mi * 16 + quad * 4;
        #pragma unroll
        for (int r = 0; r < 4; ++r)
            w2r[mi][r] = W2[hq + r];
        #pragma unroll
        for (int nj = 0; nj < 4; ++nj)
            #pragma unroll
            for (int r = 0; r < 4; ++r)
                bvr[mi][nj][r] = bvec[((size_t)(b * N_ + jtb + nj * 16 + l15)) * H_
                                      + hq + r];
    }
    float b2v = b2[0];
    __syncthreads();

    {
        int row = t >> 3, seg = t & 7;
        const float* sj = sB + (size_t)(jtb + row) * D_ + seg * 16;
        float4 a0 = ((const float4*)sj)[0], a1 = ((const float4*)sj)[1];
        float4 a2 = ((const float4*)sj)[2], a3 = ((const float4*)sj)[3];
        const float* si = &si_all[0][seg * 16];
        float4 s0 = ((const float4*)si)[0], s1 = ((const float4*)si)[1];
        float4 s2 = ((const float4*)si)[2], s3 = ((const float4*)si)[3];
        uint4 v0, v1;
        v0.x = pk2(a0.x * s0.x, a0.y * s0.y); v0.y = pk2(a0.z * s0.z, a0.w * s0.w);
        v0.z = pk2(a1.x * s1.x, a1.y * s1.y); v0.w = pk2(a1.z * s1.z, a1.w * s1.w);
        v1.x = pk2(a2.x * s2.x, a2.y * s2.y); v1.y = pk2(a2.z * s2.z, a2.w * s2.w);
        v1.z = pk2(a3.x * s3.x, a3.y * s3.y); v1.w = pk2(a3.z * s3.z, a3.w * s3.w);
        int pc0 = (seg * 2) ^ (row & 15), pc1 = (seg * 2 + 1) ^ (row & 15);
        *(uint4*)&Pl[0][row * 128 + pc0 * 8] = v0;
        *(uint4*)&Pl[0][row * 128 + pc1 * 8] = v1;
    }
    __syncthreads();

    #pragma unroll 1
    for (int i = 0; i < 16; ++i) {
        int cur = i & 1;
        if (w == 0 && i > 0) {
            float sum = b2v;
            #pragma unroll
            for (int ww = 0; ww < 8; ++ww) sum += partial[(i - 1) & 1][ww][lane];
            ascu[(size_t)(b * N_ + i0 + i - 1) * N_ + jtb + lane] = f2bf(sum);
        }
        float avc[2][4];
        #pragma unroll
        for (int mi = 0; mi < 2; ++mi) {
            int hq = w * 32 + mi * 16 + quad * 4;
            #pragma unroll
            for (int r = 0; r < 4; ++r)
                avc[mi][r] = avec[(size_t)(b * N_ + i0 + i) * H_ + hq + r];
        }
        f32x4 acc[2][4];
        #pragma unroll
        for (int mi = 0; mi < 2; ++mi)
            #pragma unroll
            for (int nj = 0; nj < 4; ++nj)
                acc[mi][nj] = (f32x4){0.f, 0.f, 0.f, 0.f};
        #pragma unroll
        for (int dk = 0; dk < 4; ++dk) {
            short8 Pf[4];
            #pragma unroll
            for (int nj = 0; nj < 4; ++nj) {
                int pcc = (dk * 4 + quad) ^ l15;
                Pf[nj] = *(const short8*)&Pl[cur][(nj * 16 + l15) * 128 + pcc * 8];
            }
            #pragma unroll
            for (int nj = 0; nj < 4; ++nj)
                #pragma unroll
                for (int mi = 0; mi < 2; ++mi)
                    acc[mi][nj] = __builtin_amdgcn_mfma_f32_16x16x32_bf16(
                        Wreg[mi][dk], Pf[nj], acc[mi][nj], 0, 0, 0);
        }
        if (i < 15) {
            int row = t >> 3, seg = t & 7;
            const float* sj = sB + (size_t)(jtb + row) * D_ + seg * 16;
            float4 a0 = ((const float4*)sj)[0], a1 = ((const float4*)sj)[1];
            float4 a2 = ((const float4*)sj)[2], a3 = ((const float4*)sj)[3];
            const float* si = &si_all[i + 1][seg * 16];
            float4 s0 = ((const float4*)si)[0], s1 = ((const float4*)si)[1];
            float4 s2 = ((const float4*)si)[2], s3 = ((const float4*)si)[3];
            uint4 v0, v1;
            v0.x = pk2(a0.x * s0.x, a0.y * s0.y); v0.y = pk2(a0.z * s0.z, a0.w * s0.w);
            v0.z = pk2(a1.x * s1.x, a1.y * s1.y); v0.w = pk2(a1.z * s1.z, a1.w * s1.w);
            v1.x = pk2(a2.x * s2.x, a2.y * s2.y); v1.y = pk2(a2.z * s2.z, a2.w * s2.w);
            v1.z = pk2(a3.x * s3.x, a3.y * s3.y); v1.w = pk2(a3.z * s3.z, a3.w * s3.w);
            int pc0 = (seg * 2) ^ (row & 15), pc1 = (seg * 2 + 1) ^ (row & 15);
            *(uint4*)&Pl[cur ^ 1][row * 128 + pc0 * 8] = v0;
            *(uint4*)&Pl[cur ^ 1][row * 128 + pc1 * 8] = v1;
        }
        float rs[4];
        #pragma unroll
        for (int nj = 0; nj < 4; ++nj) rs[nj] = 0.f;
        #pragma unroll
        for (int mi = 0; mi < 2; ++mi)
            #pragma unroll
            for (int nj = 0; nj < 4; ++nj)
                #pragma unroll
                for (int r = 0; r < 4; ++r) {
                    float z = acc[mi][nj][r] + avc[mi][r] + bvr[mi][nj][r];
                    rs[nj] = fmaf(fmaxf(z, 0.f), w2r[mi][r], rs[nj]);
                }
        #pragma unroll
        for (int nj = 0; nj < 4; ++nj) {
            rs[nj] += __shfl_xor(rs[nj], 16);
            rs[nj] += __shfl_xor(rs[nj], 32);
        }
        float v = (quad == 0) ? rs[0] : (quad == 1) ? rs[1] : (quad == 2) ? rs[2] : rs[3];
        partial[cur][w][lane] = v;
        __syncthreads();
    }
    if (w == 0) {
        float sum = b2v;
        #pragma unroll
        for (int ww = 0; ww < 8; ++ww) sum += partial[15 & 1][ww][lane];
        ascu[(size_t)(b * N_ + i0 + 15) * N_ + jtb + lane] = f2bf(sum);
    }
}

// K2 v6: spill-free by construction. 1 row/block x 1024 blocks x 256 thr.
// W staged via async global_load_lds (no wpre registers at all, double-buffered
// Wl); thread = (cand c = t&15, 16-h slice hg = t>>4) -> acc[16] + transient
// wv ~= 50 live regs. R12-R17 showed the 512-thr version was BW-bound on
// ~38 MB/dispatch of scratch-spill traffic (44.5 us ~= 53 MB / 1.2 TB/s).
#define DC2 16
#define PADT 17
__global__ __launch_bounds__(256) void finalize_kernel(
    const float* __restrict__ s, const float* __restrict__ W1,
    const float* __restrict__ W2, const float* __restrict__ b2,
    const float* __restrict__ avec, const float* __restrict__ bvec,
    const unsigned short* __restrict__ ascu,
    float* __restrict__ ctx, float* __restrict__ gate, float* __restrict__ w)
{
    int bi = blockIdx.x;               // 1024 blocks, one (b,i) row each
    int b = bi >> 8;
    int t = threadIdx.x;               // 0..255

    __shared__ float asc[N_];                        // 1 KB
    __shared__ int cand[16];
    __shared__ __align__(16) float Pt[D_][PADT];     // 8.7 KB [d][cand]
    __shared__ __align__(16) float Wl[2][DC2 * H_];  // 32 KB dbuf [d-in-chunk][h]
    __shared__ float part[16][17];
    __shared__ float rsc[16];
    __shared__ int sel8[8];

    // --- approx scores + top-16 (thread t ranks j=t) ---
    asc[t] = bf2f(ascu[(size_t)bi * N_ + t]);
    __syncthreads();
    {
        float my = asc[t];
        int rank = 0;
        #pragma unroll 8
        for (int j2 = 0; j2 < N_; ++j2) {
            float o = asc[j2];
            rank += (o > my) || (o == my && j2 < t);
        }
        if (rank < 16) cand[rank] = t;
    }
    __syncthreads();

    const float* Wc = W1 + (size_t)2 * D_ * H_;      // W1c[d][h]

    // issue async stage of W chunk 0 (16 KB = 1024 x 16 B; 4 slots/thread,
    // wave-contiguous: slot = wave*64 + lane + k*256)
    #pragma unroll
    for (int k = 0; k < 4; ++k) {
        int slot = t + 256 * k;
        gld_lds16(Wc + slot * 4, &Wl[0][slot * 4]);
    }

    // build Pt[d][c] for the 16 candidates
    for (int e = t; e < 512; e += 256) {
        int c = e & 15, dq = e >> 4;                 // dq 0..31
        int j = cand[c];
        float4 sj = *(const float4*)(s + ((size_t)(b * N_ + j)) * D_ + dq * 4);
        float4 si = *(const float4*)(s + (size_t)bi * D_ + dq * 4);
        Pt[dq * 4 + 0][c] = si.x * sj.x;
        Pt[dq * 4 + 1][c] = si.y * sj.y;
        Pt[dq * 4 + 2][c] = si.z * sj.z;
        Pt[dq * 4 + 3][c] = si.w * sj.w;
    }

    // acc init: exact fp32 a_i[h] + b_j[h]
    int c = t & 15, hg = t >> 4;
    int h0 = hg * 16;
    int jc = cand[c];
    float acc[16];
    {
        const float* av = avec + (size_t)bi * H_ + h0;
        const float* bv = bvec + ((size_t)(b * N_ + jc)) * H_ + h0;
        #pragma unroll
        for (int m4 = 0; m4 < 4; ++m4) {
            float4 a4 = *(const float4*)(av + m4 * 4);
            float4 b4 = *(const float4*)(bv + m4 * 4);
            acc[m4 * 4 + 0] = a4.x + b4.x;
            acc[m4 * 4 + 1] = a4.y + b4.y;
            acc[m4 * 4 + 2] = a4.z + b4.z;
            acc[m4 * 4 + 3] = a4.w + b4.w;
        }
    }
    __syncthreads();   // drains chunk-0 DMA (vmcnt(0) before barrier) + Pt

    // --- K-chunked GEMM, async double-buffered W ---
    #pragma unroll 1
    for (int ch = 0; ch < 8; ++ch) {
        int cur = ch & 1;
        if (ch < 7) {   // issue next chunk's DMA into the other buffer
            const float* src = Wc + (size_t)(ch + 1) * DC2 * H_;
            #pragma unroll
            for (int k = 0; k < 4; ++k) {
                int slot = t + 256 * k;
                gld_lds16(src + slot * 4, &Wl[cur ^ 1][slot * 4]);
            }
        }
        int d0 = ch * DC2;
        #pragma unroll
        for (int d = 0; d < DC2; ++d) {
            float pv = Pt[d0 + d][c];
            float wv[16];
            *(float4*)&wv[0]  = *(const float4*)&Wl[cur][d * H_ + h0];
            *(float4*)&wv[4]  = *(const float4*)&Wl[cur][d * H_ + h0 + 4];
            *(float4*)&wv[8]  = *(const float4*)&Wl[cur][d * H_ + h0 + 8];
            *(float4*)&wv[12] = *(const float4*)&Wl[cur][d * H_ + h0 + 12];
            #pragma unroll
            for (int m = 0; m < 16; ++m)
                acc[m] = fmaf(pv, wv[m], acc[m]);
        }
        __syncthreads();   // drains next chunk's DMA; guards buffer swap
    }

    // --- epilogue: relu * W2 partial, reduce over 16 hg groups ---
    {
        float w2v[16];
        *(float4*)&w2v[0]  = *(const float4*)(W2 + h0);
        *(float4*)&w2v[4]  = *(const float4*)(W2 + h0 + 4);
        *(float4*)&w2v[8]  = *(const float4*)(W2 + h0 + 8);
        *(float4*)&w2v[12] = *(const float4*)(W2 + h0 + 12);
        float sc = 0.f;
        #pragma unroll
        for (int m = 0; m < 16; ++m)
            sc = fmaf(fmaxf(acc[m], 0.f), w2v[m], sc);
        part[c][hg] = sc;
    }
    __syncthreads();
    if (t < 16) {
        float sum = b2[0];
        #pragma unroll
        for (int m = 0; m < 16; ++m) sum += part[t][m];
        rsc[t] = sum;
    }
    __syncthreads();

    // top-8 among 16 exact scores, tiebreak smaller original index
    if (t < 16) {
        float my = rsc[t]; int myj = cand[t];
        int rank = 0;
        #pragma unroll
        for (int c2 = 0; c2 < 16; ++c2) {
            float o = rsc[c2]; int oj = cand[c2];
            rank += (o > my) || (o == my && oj < myj);
        }
        if (rank < 8) sel8[rank] = myj;
    }
    __syncthreads();

    // gate / w (256 j, one per thread)
    {
        float gv = 0.f;
        #pragma unroll
        for (int m = 0; m < 8; ++m)
            gv = (t == sel8[m]) ? 1.f : gv;
        gate[(size_t)bi * N_ + t] = gv;
        w[(size_t)bi * N_ + t]    = gv * 0.125f;
    }
    // ctx (128 d)
    if (t < 128) {
        float a = 0.f;
        #pragma unroll
        for (int m = 0; m < 8; ++m)
            a += s[((size_t)(b * N_ + sel8[m])) * D_ + t];
        ctx[(size_t)bi * D_ + t] = a * 0.125f;
    }
}

extern "C" void kernel_launch(void* const* d_in, const int* in_sizes, int n_in,
                              void* d_out, int out_size, void* d_ws, size_t ws_size,
                              hipStream_t stream)
{
    const float* s  = (const float*)d_in[0];
    const float* W1 = (const float*)d_in[1];
    const float* b1 = (const float*)d_in[2];
    const float* W2 = (const float*)d_in[3];
    const float* b2 = (const float*)d_in[4];

    float* avec = (float*)d_ws;                                           // 262144 f
    float* bvec = avec + (size_t)B_ * N_ * H_;                            // 262144 f
    unsigned short* ascu = (unsigned short*)(bvec + (size_t)B_ * N_ * H_);// 262144 us
    unsigned short* Wtu  = ascu + (size_t)B_ * N_ * N_;                   // 32768 us

    float* ctx  = (float*)d_out;
    float* gate = ctx + (size_t)B_ * N_ * D_;
    float* wout = gate + (size_t)B_ * N_ * N_;

    pre_kernel<<<640, 256, 0, stream>>>(s, W1, b1, avec, bvec, Wtu);
    approx_scores<<<256, 512, 0, stream>>>(s, Wtu, W2, b2, avec, bvec, ascu);
    finalize_kernel<<<B_ * N_, 256, 0, stream>>>(s, W1, W2, b2, avec, bvec, ascu,
                                                 ctx, gate, wout);
}